// Round 3
// baseline (145.086 us; speedup 1.0000x reference)
//
#include <hip/hip_runtime.h>
#include <hip/hip_bf16.h>

// Problem constants (from reference setup_inputs)
#define B_  16
#define S_  1024
#define D_  300
#define K_  64           // hidden_set_size == compressed dim
#define O_  256          // outputs per batch
#define M_  (B_*S_)      // 16384 rows (b,s)

typedef __attribute__((ext_vector_type(8)))  short s8b;    // 8 x bf16 (4 VGPRs)
typedef __attribute__((ext_vector_type(4)))  float f32x4;
typedef __attribute__((ext_vector_type(16))) float f32x16;

#define MFMA16(a,b,c) __builtin_amdgcn_mfma_f32_16x16x32_bf16((a),(b),(c),0,0,0)
#define MFMA32(a,b,c) __builtin_amdgcn_mfma_f32_32x32x16_bf16((a),(b),(c),0,0,0)

__device__ __forceinline__ unsigned short bf16_bits(float f) {
    return __builtin_bit_cast(unsigned short, __float2bfloat16(f));
}

// Pack two float4s into an s8b bf16 fragment (same rounding everywhere).
__device__ __forceinline__ s8b pack8(float4 f0, float4 f1) {
    union { unsigned short us[8]; s8b v; } pk;
    pk.us[0]=bf16_bits(f0.x); pk.us[1]=bf16_bits(f0.y);
    pk.us[2]=bf16_bits(f0.z); pk.us[3]=bf16_bits(f0.w);
    pk.us[4]=bf16_bits(f1.x); pk.us[5]=bf16_bits(f1.y);
    pk.us[6]=bf16_bits(f1.z); pk.us[7]=bf16_bits(f1.w);
    return pk.v;
}

// ---------------------------------------------------------------------------
// Kernel 1 (merged head): three block roles in ONE dispatch (proven R2).
//   blocks [0, 1024)      : compress GEMM  Xc = bf16(Xs @ W^T + b)
//   blocks [1024, 1536)   : H f32 -> bf16 into Hb (amortized 32x by k_fused)
//   block  1536           : out[16*256] = 0 (k_fused accumulates atomically)
// ---------------------------------------------------------------------------
#define C_BLK 1024    // M_/16 compress blocks
#define H_BLK 512     // 256*64*64/8/256 convert blocks

__global__ __launch_bounds__(256) void k_head(
        const float* __restrict__ Xs,
        const float* __restrict__ W,
        const float* __restrict__ bias,
        const float* __restrict__ H,
        __hip_bfloat16* __restrict__ Xc,
        __hip_bfloat16* __restrict__ Hb,
        float* __restrict__ out) {
    int bx = blockIdx.x, tid = threadIdx.x;
    if (bx >= C_BLK) {
        if (bx < C_BLK + H_BLK) {            // H flat f32 -> bf16
            int g = ((bx - C_BLK) * 256 + tid) * 8;
            float4 f0 = *(const float4*)(H + g);
            float4 f1 = *(const float4*)(H + g + 4);
            *(uint4*)(Hb + g) = __builtin_bit_cast(uint4, pack8(f0, f1));
        } else {                             // zero out[4096]
            float4 z = {0.f,0.f,0.f,0.f};
            float4* o4 = (float4*)out;
#pragma unroll
            for (int i = 0; i < 4; ++i) o4[tid * 4 + i] = z;
        }
        return;
    }

    int w    = tid >> 6, lane = tid & 63;
    int q    = lane >> 4, r = lane & 15;
    int row0 = bx * 16;
    int col0 = w * 16;

    f32x4 acc0 = {0.f,0.f,0.f,0.f}, acc1 = {0.f,0.f,0.f,0.f};
    const float* arow = Xs + (size_t)(row0 + r) * D_;
    const float* brow = W  + (size_t)(col0 + r) * D_;
    const float4 z4 = {0.f,0.f,0.f,0.f};

#pragma unroll
    for (int ks = 0; ks < 10; ++ks) {
        int k0 = ks * 32 + q * 8;
        float4 a0 = (k0     < D_) ? *(const float4*)(arow + k0)     : z4;
        float4 a1 = (k0 + 4 < D_) ? *(const float4*)(arow + k0 + 4) : z4;
        float4 b0 = (k0     < D_) ? *(const float4*)(brow + k0)     : z4;
        float4 b1 = (k0 + 4 < D_) ? *(const float4*)(brow + k0 + 4) : z4;
        s8b av = pack8(a0, a1);
        s8b bv = pack8(b0, b1);
        if (ks & 1) acc1 = MFMA16(av, bv, acc1);
        else        acc0 = MFMA16(av, bv, acc0);
    }
    // C/D layout: col = lane&15 (out-k), row = quad*4 + i (bs)
#pragma unroll
    for (int i = 0; i < 4; ++i) {
        int orow = row0 + q * 4 + i;
        int c    = col0 + r;
        Xc[(size_t)orow * K_ + c] =
            __float2bfloat16(acc0[i] + acc1[i] + bias[c]);
    }
}

// ---------------------------------------------------------------------------
// Kernel 2: fused bipartite GEMM + relu + max-over-n + sum-over-s.
// DE-STAGED (m169 lesson: never LDS-stage data the caches already serve):
// per block-iteration the Xc working set is 8 KB, L2-resident (2 MB total)
// and L1-resident per CU (4 blocks x 8 KB = 32 KB), reused 4x by the
// block's waves -> the old LDS double-buffer + 8 barriers/block + 160B-row
// ds_reads were pure overhead.  Now: NO LDS, NO barriers.  Each wave streams
// its B-fragments straight from global with a 1-deep register prefetch
// (loads for iter it+1 issued before the MFMA cluster of iter it; the
// ~40-cyc VALU max-reduce + 8 MFMAs cover the L1/L2-hit latency).
// 32x32x16 MFMA, A = Hb (n rows), B = Xc (bs cols):
//   C col = lane&31 = bs, row = (reg&3)+8*(reg>>2)+4*(lane>>5) = n.
// B-fragment load: lane reads Xc[row0 + it*32 + (lane&31)][k], where its
// k-chunk (2*ks + lane>>5)*8 = ks*16 + (lane>>5)*8 folds into the base ptr.
// Grid: 16 batches x 64 o-quads x 2 s-halves = 2048 blocks.
// ---------------------------------------------------------------------------
__global__ __launch_bounds__(256, 4) void k_fused(
        const __hip_bfloat16* __restrict__ Xc,
        const __hip_bfloat16* __restrict__ Hb,
        float* __restrict__ out) {
    int tid   = threadIdx.x;
    int w     = tid >> 6, lane = tid & 63;
    int half  = lane >> 5, l31 = lane & 31;
    int bx    = blockIdx.x;
    int batch = bx >> 7;          // 0..15
    int oq    = (bx >> 1) & 63;   // 0..63
    int sh    = bx & 1;           // 0..1 : which 512-row half
    int o     = oq * 4 + w;

    // Preload A fragments (Hb, this wave's o): 2 n-tiles x 4 k-steps.
    // A layout: row = lane&31 (n), k = ks*16 + (lane>>5)*8 + j.
    s8b af[2][4];
#pragma unroll
    for (int nt = 0; nt < 2; ++nt) {
        const __hip_bfloat16* hrow =
            Hb + (size_t)(o * 64 + nt * 32 + l31) * 64 + half * 8;
#pragma unroll
        for (int ks = 0; ks < 4; ++ks)
            af[nt][ks] = __builtin_bit_cast(s8b, *(const uint4*)(hrow + ks * 16));
    }

    // Lane's Xc base: row = (batch,sh-half) + l31, k-chunk half*8.
    const __hip_bfloat16* xlane =
        Xc + ((size_t)batch * S_ + (size_t)sh * 512 + l31) * K_ + half * 8;

    // 1-deep register prefetch over 16 iterations of 32 bs-rows each.
    uint4 cur[4], nxt[4];
#pragma unroll
    for (int ks = 0; ks < 4; ++ks)
        cur[ks] = *(const uint4*)(xlane + ks * 16);

    float total = 0.0f;
#pragma unroll 2
    for (int it = 0; it < 16; ++it) {
        if (it < 15) {
            const __hip_bfloat16* p = xlane + (size_t)(it + 1) * 32 * K_;
#pragma unroll
            for (int ks = 0; ks < 4; ++ks)
                nxt[ks] = *(const uint4*)(p + ks * 16);
        }

        f32x16 a0 = {0.f,0.f,0.f,0.f,0.f,0.f,0.f,0.f,
                     0.f,0.f,0.f,0.f,0.f,0.f,0.f,0.f};
        f32x16 a1 = a0;
#pragma unroll
        for (int ks = 0; ks < 4; ++ks) {
            s8b b = __builtin_bit_cast(s8b, cur[ks]);
            a0 = MFMA32(af[0][ks], b, a0);
            a1 = MFMA32(af[1][ks], b, a1);
        }

        // Max over 32 in-lane n-values: 4 max3-fusable chains.
        float m0 = fmaxf(fmaxf(a0[0], a0[1]), a0[2]);
        m0 = fmaxf(fmaxf(m0, a0[3]), a0[4]);
        m0 = fmaxf(fmaxf(m0, a0[5]), a0[6]);
        m0 = fmaxf(m0, a0[7]);
        float m1 = fmaxf(fmaxf(a0[8], a0[9]), a0[10]);
        m1 = fmaxf(fmaxf(m1, a0[11]), a0[12]);
        m1 = fmaxf(fmaxf(m1, a0[13]), a0[14]);
        m1 = fmaxf(m1, a0[15]);
        float m2 = fmaxf(fmaxf(a1[0], a1[1]), a1[2]);
        m2 = fmaxf(fmaxf(m2, a1[3]), a1[4]);
        m2 = fmaxf(fmaxf(m2, a1[5]), a1[6]);
        m2 = fmaxf(m2, a1[7]);
        float m3 = fmaxf(fmaxf(a1[8], a1[9]), a1[10]);
        m3 = fmaxf(fmaxf(m3, a1[11]), a1[12]);
        m3 = fmaxf(fmaxf(m3, a1[13]), a1[14]);
        m3 = fmaxf(m3, a1[15]);
        float v = fmaxf(fmaxf(fmaxf(m0, m1), fmaxf(m2, m3)), 0.0f);
        v = fmaxf(v, __shfl_xor(v, 32));   // other half's 32 n-rows
        total += v;                        // lane's bs col = it*32 + l31

#pragma unroll
        for (int ks = 0; ks < 4; ++ks) cur[ks] = nxt[ks];
    }

    // Sum over the 32 bs columns (halves hold identical totals).
    total += __shfl_xor(total, 1);
    total += __shfl_xor(total, 2);
    total += __shfl_xor(total, 4);
    total += __shfl_xor(total, 8);
    total += __shfl_xor(total, 16);
    if (lane == 0) atomicAdd(out + batch * O_ + o, total);
}

// ---------------------------------------------------------------------------
extern "C" void kernel_launch(void* const* d_in, const int* in_sizes, int n_in,
                              void* d_out, int out_size, void* d_ws, size_t ws_size,
                              hipStream_t stream) {
    const float* Xs   = (const float*)d_in[0];   // [16,1024,300]
    const float* W    = (const float*)d_in[1];   // [64,300]
    const float* bias = (const float*)d_in[2];   // [64]
    const float* H    = (const float*)d_in[3];   // [256,64,64]
    float* out = (float*)d_out;                  // [16,256] f32

    char* ws = (char*)d_ws;
    __hip_bfloat16* Hb = (__hip_bfloat16*)(ws);            // 2,097,152 B
    __hip_bfloat16* Xc = (__hip_bfloat16*)(ws + 2097152);  // 2,097,152 B

    k_head <<<C_BLK + H_BLK + 1, 256, 0, stream>>>(Xs, W, bias, H, Xc, Hb, out);
    k_fused<<<B_ * (O_ / 4) * 2, 256, 0, stream>>>(Xc, Hb, out);
}

// Round 4
// 108.559 us; speedup vs baseline: 1.3365x; 1.3365x over previous
//
#include <hip/hip_runtime.h>
#include <hip/hip_bf16.h>

// Problem constants (from reference setup_inputs)
#define B_  16
#define S_  1024
#define D_  300
#define K_  64           // hidden_set_size == compressed dim
#define O_  256          // outputs per batch
#define M_  (B_*S_)      // 16384 rows (b,s)

#define LROW 80          // LDS row stride in elements (160 B): phase groups of
                         // 8 lanes hit banks {0,8,16,24} twice -> 2-way = free

typedef __attribute__((ext_vector_type(8)))  short s8b;    // 8 x bf16 (4 VGPRs)
typedef __attribute__((ext_vector_type(4)))  float f32x4;
typedef __attribute__((ext_vector_type(16))) float f32x16;

#define MFMA16(a,b,c) __builtin_amdgcn_mfma_f32_16x16x32_bf16((a),(b),(c),0,0,0)
#define MFMA32(a,b,c) __builtin_amdgcn_mfma_f32_32x32x16_bf16((a),(b),(c),0,0,0)

__device__ __forceinline__ unsigned short bf16_bits(float f) {
    return __builtin_bit_cast(unsigned short, __float2bfloat16(f));
}

// Pack two float4s into an s8b bf16 fragment (same rounding everywhere).
__device__ __forceinline__ s8b pack8(float4 f0, float4 f1) {
    union { unsigned short us[8]; s8b v; } pk;
    pk.us[0]=bf16_bits(f0.x); pk.us[1]=bf16_bits(f0.y);
    pk.us[2]=bf16_bits(f0.z); pk.us[3]=bf16_bits(f0.w);
    pk.us[4]=bf16_bits(f1.x); pk.us[5]=bf16_bits(f1.y);
    pk.us[6]=bf16_bits(f1.z); pk.us[7]=bf16_bits(f1.w);
    return pk.v;
}

// ---------------------------------------------------------------------------
// Kernel 1 (merged head): three block roles in ONE dispatch (proven R2).
//   blocks [0, 1024)      : compress GEMM  Xc = bf16(Xs @ W^T + b)
//   blocks [1024, 1536)   : H f32 -> bf16 into Hb (amortized 32x by k_fused)
//   block  1536           : out[16*256] = 0 (k_fused accumulates atomically)
// ---------------------------------------------------------------------------
#define C_BLK 1024    // M_/16 compress blocks
#define H_BLK 512     // 256*64*64/8/256 convert blocks

__global__ __launch_bounds__(256) void k_head(
        const float* __restrict__ Xs,
        const float* __restrict__ W,
        const float* __restrict__ bias,
        const float* __restrict__ H,
        __hip_bfloat16* __restrict__ Xc,
        __hip_bfloat16* __restrict__ Hb,
        float* __restrict__ out) {
    int bx = blockIdx.x, tid = threadIdx.x;
    if (bx >= C_BLK) {
        if (bx < C_BLK + H_BLK) {            // H flat f32 -> bf16
            int g = ((bx - C_BLK) * 256 + tid) * 8;
            float4 f0 = *(const float4*)(H + g);
            float4 f1 = *(const float4*)(H + g + 4);
            *(uint4*)(Hb + g) = __builtin_bit_cast(uint4, pack8(f0, f1));
        } else {                             // zero out[4096]
            float4 z = {0.f,0.f,0.f,0.f};
            float4* o4 = (float4*)out;
#pragma unroll
            for (int i = 0; i < 4; ++i) o4[tid * 4 + i] = z;
        }
        return;
    }

    int w    = tid >> 6, lane = tid & 63;
    int q    = lane >> 4, r = lane & 15;
    int row0 = bx * 16;
    int col0 = w * 16;

    f32x4 acc0 = {0.f,0.f,0.f,0.f}, acc1 = {0.f,0.f,0.f,0.f};
    const float* arow = Xs + (size_t)(row0 + r) * D_;
    const float* brow = W  + (size_t)(col0 + r) * D_;
    const float4 z4 = {0.f,0.f,0.f,0.f};

#pragma unroll
    for (int ks = 0; ks < 10; ++ks) {
        int k0 = ks * 32 + q * 8;
        float4 a0 = (k0     < D_) ? *(const float4*)(arow + k0)     : z4;
        float4 a1 = (k0 + 4 < D_) ? *(const float4*)(arow + k0 + 4) : z4;
        float4 b0 = (k0     < D_) ? *(const float4*)(brow + k0)     : z4;
        float4 b1 = (k0 + 4 < D_) ? *(const float4*)(brow + k0 + 4) : z4;
        s8b av = pack8(a0, a1);
        s8b bv = pack8(b0, b1);
        if (ks & 1) acc1 = MFMA16(av, bv, acc1);
        else        acc0 = MFMA16(av, bv, acc0);
    }
    // C/D layout: col = lane&15 (out-k), row = quad*4 + i (bs)
#pragma unroll
    for (int i = 0; i < 4; ++i) {
        int orow = row0 + q * 4 + i;
        int c    = col0 + r;
        Xc[(size_t)orow * K_ + c] =
            __float2bfloat16(acc0[i] + acc1[i] + bias[c]);
    }
}

// ---------------------------------------------------------------------------
// Kernel 2: fused bipartite GEMM + relu + max-over-n + sum-over-s.
// STAGED (R3 lesson: LDS here is a BROADCAST amortizer, not redundant
// staging — de-staging quadrupled L2 traffic to ~512 MB and went
// latency-bound at 73 us).  This round: 8 waves / 8 o's per block (512 thr)
// so each staged 8 KB slice feeds 8 consumers instead of 4:
//   - global/L2 Xc traffic halves (128 -> 64 MB),
//   - staging cost per thread halves (1 uint4 + 1 ds_write per slice),
//   - occupancy stays 32 waves/CU (4 blocks x 8 waves; LDS 80 KB/CU).
// Inner loop byte-identical to the proven R0/R2 version: double-buffered
// LDS (LROW=80 -> free 2-way phase conflicts only), register prefetch of
// slice s+1 during compute of slice s, ONE barrier per slice.
// 32x32x16 MFMA, A = Hb (n rows), B = Xc (bs cols):
//   C col = lane&31 = bs, row = (reg&3)+8*(reg>>2)+4*(lane>>5) = n.
// Grid: 16 batches x 32 o-octets x 2 s-halves = 1024 blocks; LDS 20,480 B.
// ---------------------------------------------------------------------------
__global__ __launch_bounds__(512, 4) void k_fused(
        const __hip_bfloat16* __restrict__ Xc,
        const __hip_bfloat16* __restrict__ Hb,
        float* __restrict__ out) {
    __shared__ __hip_bfloat16 lx[2][64 * LROW];   // 2 x 10,240 B
    int tid   = threadIdx.x;
    int w     = tid >> 6, lane = tid & 63;
    int half  = lane >> 5, l31 = lane & 31;
    int bx    = blockIdx.x;
    int batch = bx >> 6;          // 0..15
    int oq    = (bx >> 1) & 31;   // 0..31
    int sh    = bx & 1;           // 0..1 : which 512-row half
    int o     = oq * 8 + w;       // this wave's output column

    // Preload A fragments (Hb, this wave's o): 2 n-tiles x 4 k-steps.
    // A layout: row = lane&31 (n), k = ks*16 + (lane>>5)*8 + j.
    s8b af[2][4];
#pragma unroll
    for (int nt = 0; nt < 2; ++nt) {
        const __hip_bfloat16* hrow =
            Hb + (size_t)(o * 64 + nt * 32 + l31) * 64 + half * 8;
#pragma unroll
        for (int ks = 0; ks < 4; ++ks)
            af[nt][ks] = __builtin_bit_cast(s8b, *(const uint4*)(hrow + ks * 16));
    }

    const __hip_bfloat16* xbase =
        Xc + ((size_t)batch * S_ + (size_t)sh * 512) * K_;

    // Staging map: 512 thr, 64 rows x 8 chunks of 16 B -> 1 uint4/thread.
    int sr = tid >> 3, sc = tid & 7;

    // Stage slice 0 into buffer 0.
    {
        uint4 v = *(const uint4*)(xbase + (size_t)sr * K_ + sc * 8);
        *(uint4*)(&lx[0][sr * LROW + sc * 8]) = v;
    }
    __syncthreads();

    float total = 0.0f;
    for (int s = 0; s < 8; ++s) {
        uint4 npf;
        if (s < 7) {                           // prefetch slice s+1 -> regs
            const __hip_bfloat16* nsrc = xbase + (size_t)(s + 1) * 64 * K_;
            npf = *(const uint4*)(nsrc + (size_t)sr * K_ + sc * 8);
        }
        const __hip_bfloat16* buf = lx[s & 1];
#pragma unroll
        for (int t = 0; t < 2; ++t) {
            int rr = t * 32 + l31;
            // B layout: col = lane&31 (bs row rr), k = (lane>>5)*8 + j;
            // step ks covers k = 16*ks .. 16*ks+15 -> chunk 2*ks+half.
            s8b bf[4];
#pragma unroll
            for (int ks = 0; ks < 4; ++ks)
                bf[ks] = __builtin_bit_cast(s8b,
                    *(const uint4*)(&buf[rr * LROW + (2 * ks + half) * 8]));

            f32x16 a0 = {0.f,0.f,0.f,0.f,0.f,0.f,0.f,0.f,
                         0.f,0.f,0.f,0.f,0.f,0.f,0.f,0.f};
            f32x16 a1 = a0;
#pragma unroll
            for (int ks = 0; ks < 4; ++ks) {
                a0 = MFMA32(af[0][ks], bf[ks], a0);
                a1 = MFMA32(af[1][ks], bf[ks], a1);
            }
            // Max over 32 in-lane n-values: 4 max3-fusable chains.
            float m0 = fmaxf(fmaxf(a0[0], a0[1]), a0[2]);
            m0 = fmaxf(fmaxf(m0, a0[3]), a0[4]);
            m0 = fmaxf(fmaxf(m0, a0[5]), a0[6]);
            m0 = fmaxf(m0, a0[7]);
            float m1 = fmaxf(fmaxf(a0[8], a0[9]), a0[10]);
            m1 = fmaxf(fmaxf(m1, a0[11]), a0[12]);
            m1 = fmaxf(fmaxf(m1, a0[13]), a0[14]);
            m1 = fmaxf(m1, a0[15]);
            float m2 = fmaxf(fmaxf(a1[0], a1[1]), a1[2]);
            m2 = fmaxf(fmaxf(m2, a1[3]), a1[4]);
            m2 = fmaxf(fmaxf(m2, a1[5]), a1[6]);
            m2 = fmaxf(m2, a1[7]);
            float m3 = fmaxf(fmaxf(a1[8], a1[9]), a1[10]);
            m3 = fmaxf(fmaxf(m3, a1[11]), a1[12]);
            m3 = fmaxf(fmaxf(m3, a1[13]), a1[14]);
            m3 = fmaxf(m3, a1[15]);
            float v = fmaxf(fmaxf(fmaxf(m0, m1), fmaxf(m2, m3)), 0.0f);
            v = fmaxf(v, __shfl_xor(v, 32));   // other half's 32 n-rows
            total += v;                        // lane's bs col = rr (replicated)
        }
        if (s < 7) {                           // publish slice s+1, 1 barrier
            *(uint4*)(&lx[(s + 1) & 1][sr * LROW + sc * 8]) = npf;
            __syncthreads();
        }
    }
    // Sum over the 32 bs columns (halves hold identical totals).
    total += __shfl_xor(total, 1);
    total += __shfl_xor(total, 2);
    total += __shfl_xor(total, 4);
    total += __shfl_xor(total, 8);
    total += __shfl_xor(total, 16);
    if (lane == 0) atomicAdd(out + batch * O_ + o, total);
}

// ---------------------------------------------------------------------------
extern "C" void kernel_launch(void* const* d_in, const int* in_sizes, int n_in,
                              void* d_out, int out_size, void* d_ws, size_t ws_size,
                              hipStream_t stream) {
    const float* Xs   = (const float*)d_in[0];   // [16,1024,300]
    const float* W    = (const float*)d_in[1];   // [64,300]
    const float* bias = (const float*)d_in[2];   // [64]
    const float* H    = (const float*)d_in[3];   // [256,64,64]
    float* out = (float*)d_out;                  // [16,256] f32

    char* ws = (char*)d_ws;
    __hip_bfloat16* Hb = (__hip_bfloat16*)(ws);            // 2,097,152 B
    __hip_bfloat16* Xc = (__hip_bfloat16*)(ws + 2097152);  // 2,097,152 B

    k_head <<<C_BLK + H_BLK + 1, 256, 0, stream>>>(Xs, W, bias, H, Xc, Hb, out);
    k_fused<<<B_ * (O_ / 8) * 2, 512, 0, stream>>>(Xc, Hb, out);
}

// Round 5
// 108.300 us; speedup vs baseline: 1.3397x; 1.0024x over previous
//
#include <hip/hip_runtime.h>
#include <hip/hip_bf16.h>

// Problem constants (from reference setup_inputs)
#define B_  16
#define S_  1024
#define D_  300
#define K_  64           // hidden_set_size == compressed dim
#define O_  256          // outputs per batch
#define M_  (B_*S_)      // 16384 rows (b,s)

#define LROW 80          // LDS row stride in elements (160 B): 64 lanes x 4
                         // dwords land 8-per-bank -> data-return-optimal

typedef __attribute__((ext_vector_type(8)))  short s8b;    // 8 x bf16 (4 VGPRs)
typedef __attribute__((ext_vector_type(4)))  float f32x4;
typedef __attribute__((ext_vector_type(16))) float f32x16;

#define MFMA16(a,b,c) __builtin_amdgcn_mfma_f32_16x16x32_bf16((a),(b),(c),0,0,0)
#define MFMA32(a,b,c) __builtin_amdgcn_mfma_f32_32x32x16_bf16((a),(b),(c),0,0,0)

__device__ __forceinline__ unsigned short bf16_bits(float f) {
    return __builtin_bit_cast(unsigned short, __float2bfloat16(f));
}

// Pack two float4s into an s8b bf16 fragment (same rounding everywhere).
__device__ __forceinline__ s8b pack8(float4 f0, float4 f1) {
    union { unsigned short us[8]; s8b v; } pk;
    pk.us[0]=bf16_bits(f0.x); pk.us[1]=bf16_bits(f0.y);
    pk.us[2]=bf16_bits(f0.z); pk.us[3]=bf16_bits(f0.w);
    pk.us[4]=bf16_bits(f1.x); pk.us[5]=bf16_bits(f1.y);
    pk.us[6]=bf16_bits(f1.z); pk.us[7]=bf16_bits(f1.w);
    return pk.v;
}

// relu-max over the 32 in-lane n-values of an MFMA32 acc pair.
__device__ __forceinline__ float maxreduce32(const f32x16& a0, const f32x16& a1) {
    float m0 = fmaxf(fmaxf(a0[0], a0[1]), a0[2]);
    m0 = fmaxf(fmaxf(m0, a0[3]), a0[4]);
    m0 = fmaxf(fmaxf(m0, a0[5]), a0[6]);
    m0 = fmaxf(m0, a0[7]);
    float m1 = fmaxf(fmaxf(a0[8], a0[9]), a0[10]);
    m1 = fmaxf(fmaxf(m1, a0[11]), a0[12]);
    m1 = fmaxf(fmaxf(m1, a0[13]), a0[14]);
    m1 = fmaxf(m1, a0[15]);
    float m2 = fmaxf(fmaxf(a1[0], a1[1]), a1[2]);
    m2 = fmaxf(fmaxf(m2, a1[3]), a1[4]);
    m2 = fmaxf(fmaxf(m2, a1[5]), a1[6]);
    m2 = fmaxf(m2, a1[7]);
    float m3 = fmaxf(fmaxf(a1[8], a1[9]), a1[10]);
    m3 = fmaxf(fmaxf(m3, a1[11]), a1[12]);
    m3 = fmaxf(fmaxf(m3, a1[13]), a1[14]);
    m3 = fmaxf(m3, a1[15]);
    return fmaxf(fmaxf(fmaxf(m0, m1), fmaxf(m2, m3)), 0.0f);
}

// ---------------------------------------------------------------------------
// Kernel 1 (merged head): three block roles in ONE dispatch (proven R2).
//   blocks [0, 1024)      : compress GEMM  Xc = bf16(Xs @ W^T + b)
//   blocks [1024, 1536)   : H f32 -> bf16 into Hb (amortized 32x by k_fused)
//   block  1536           : out[16*256] = 0 (k_fused accumulates atomically)
// ---------------------------------------------------------------------------
#define C_BLK 1024    // M_/16 compress blocks
#define H_BLK 512     // 256*64*64/8/256 convert blocks

__global__ __launch_bounds__(256) void k_head(
        const float* __restrict__ Xs,
        const float* __restrict__ W,
        const float* __restrict__ bias,
        const float* __restrict__ H,
        __hip_bfloat16* __restrict__ Xc,
        __hip_bfloat16* __restrict__ Hb,
        float* __restrict__ out) {
    int bx = blockIdx.x, tid = threadIdx.x;
    if (bx >= C_BLK) {
        if (bx < C_BLK + H_BLK) {            // H flat f32 -> bf16
            int g = ((bx - C_BLK) * 256 + tid) * 8;
            float4 f0 = *(const float4*)(H + g);
            float4 f1 = *(const float4*)(H + g + 4);
            *(uint4*)(Hb + g) = __builtin_bit_cast(uint4, pack8(f0, f1));
        } else {                             // zero out[4096]
            float4 z = {0.f,0.f,0.f,0.f};
            float4* o4 = (float4*)out;
#pragma unroll
            for (int i = 0; i < 4; ++i) o4[tid * 4 + i] = z;
        }
        return;
    }

    int w    = tid >> 6, lane = tid & 63;
    int q    = lane >> 4, r = lane & 15;
    int row0 = bx * 16;
    int col0 = w * 16;

    f32x4 acc0 = {0.f,0.f,0.f,0.f}, acc1 = {0.f,0.f,0.f,0.f};
    const float* arow = Xs + (size_t)(row0 + r) * D_;
    const float* brow = W  + (size_t)(col0 + r) * D_;
    const float4 z4 = {0.f,0.f,0.f,0.f};

#pragma unroll
    for (int ks = 0; ks < 10; ++ks) {
        int k0 = ks * 32 + q * 8;
        float4 a0 = (k0     < D_) ? *(const float4*)(arow + k0)     : z4;
        float4 a1 = (k0 + 4 < D_) ? *(const float4*)(arow + k0 + 4) : z4;
        float4 b0 = (k0     < D_) ? *(const float4*)(brow + k0)     : z4;
        float4 b1 = (k0 + 4 < D_) ? *(const float4*)(brow + k0 + 4) : z4;
        s8b av = pack8(a0, a1);
        s8b bv = pack8(b0, b1);
        if (ks & 1) acc1 = MFMA16(av, bv, acc1);
        else        acc0 = MFMA16(av, bv, acc0);
    }
    // C/D layout: col = lane&15 (out-k), row = quad*4 + i (bs)
#pragma unroll
    for (int i = 0; i < 4; ++i) {
        int orow = row0 + q * 4 + i;
        int c    = col0 + r;
        Xc[(size_t)orow * K_ + c] =
            __float2bfloat16(acc0[i] + acc1[i] + bias[c]);
    }
}

// ---------------------------------------------------------------------------
// Kernel 2: fused bipartite GEMM + relu + max-over-n + sum-over-s.
// PHASE-SPLIT schedule (T3+T5 port; R0-R4's single-barrier 2-phase loop is
// pinned at 38% MfmaUtil = the measured 2-phase structural ceiling).
// Per slice, 2 MFMA phases (t=0,1), each clustered as:
//   {mem section} -> s_barrier -> lgkmcnt(0)+sched_barrier -> setprio(1)
//   -> 8 MFMA -> setprio(0) -> s_barrier
// Raw s_barrier (no vmcnt drain) so the slice s+1 prefetch load stays in
// flight across phases; __syncthreads only at buffer publish (the single
// correctness barrier, unchanged from R4).  Max-reduces moved into the mem
// sections so other blocks' MFMA phases (4 independent blocks/CU at skewed
// barrier phases) overlap them — the role diversity setprio arbitrates.
// Data/layout/numerics byte-identical to R4.
// Grid: 16 batches x 32 o-octets x 2 s-halves = 1024 blocks; 8 waves;
// LDS 2 x 10,240 B.
// ---------------------------------------------------------------------------
__global__ __launch_bounds__(512, 4) void k_fused(
        const __hip_bfloat16* __restrict__ Xc,
        const __hip_bfloat16* __restrict__ Hb,
        float* __restrict__ out) {
    __shared__ __hip_bfloat16 lx[2][64 * LROW];   // 2 x 10,240 B
    int tid   = threadIdx.x;
    int w     = tid >> 6, lane = tid & 63;
    int half  = lane >> 5, l31 = lane & 31;
    int bx    = blockIdx.x;
    int batch = bx >> 6;          // 0..15
    int oq    = (bx >> 1) & 31;   // 0..31
    int sh    = bx & 1;           // 0..1 : which 512-row half
    int o     = oq * 8 + w;       // this wave's output column

    // Preload A fragments (Hb, this wave's o): 2 n-tiles x 4 k-steps.
    // A layout: row = lane&31 (n), k = ks*16 + (lane>>5)*8 + j.
    s8b af[2][4];
#pragma unroll
    for (int nt = 0; nt < 2; ++nt) {
        const __hip_bfloat16* hrow =
            Hb + (size_t)(o * 64 + nt * 32 + l31) * 64 + half * 8;
#pragma unroll
        for (int ks = 0; ks < 4; ++ks)
            af[nt][ks] = __builtin_bit_cast(s8b, *(const uint4*)(hrow + ks * 16));
    }

    const __hip_bfloat16* xbase =
        Xc + ((size_t)batch * S_ + (size_t)sh * 512) * K_;

    // Staging map: 512 thr, 64 rows x 8 chunks of 16 B -> 1 uint4/thread.
    int sr = tid >> 3, sc = tid & 7;

    // Stage slice 0 into buffer 0.
    {
        uint4 v = *(const uint4*)(xbase + (size_t)sr * K_ + sc * 8);
        *(uint4*)(&lx[0][sr * LROW + sc * 8]) = v;
    }
    __syncthreads();

    float total = 0.0f;
    for (int s = 0; s < 8; ++s) {
        const __hip_bfloat16* buf = lx[s & 1];

        // ---- phase A mem: t=0 ds_reads + slice s+1 prefetch issue ----
        s8b bf0[4];
#pragma unroll
        for (int ks = 0; ks < 4; ++ks)
            bf0[ks] = __builtin_bit_cast(s8b,
                *(const uint4*)(&buf[l31 * LROW + (2 * ks + half) * 8]));
        uint4 npf;
        if (s < 7) {
            const __hip_bfloat16* nsrc = xbase + (size_t)(s + 1) * 64 * K_;
            npf = *(const uint4*)(nsrc + (size_t)sr * K_ + sc * 8);
        }
        __builtin_amdgcn_s_barrier();
        asm volatile("s_waitcnt lgkmcnt(0)" ::: "memory");
        __builtin_amdgcn_sched_barrier(0);

        // ---- phase A MFMA cluster ----
        f32x16 pa0 = {0.f,0.f,0.f,0.f,0.f,0.f,0.f,0.f,
                      0.f,0.f,0.f,0.f,0.f,0.f,0.f,0.f};
        f32x16 pa1 = pa0;
        __builtin_amdgcn_s_setprio(1);
#pragma unroll
        for (int ks = 0; ks < 4; ++ks) {
            pa0 = MFMA32(af[0][ks], bf0[ks], pa0);
            pa1 = MFMA32(af[1][ks], bf0[ks], pa1);
        }
        __builtin_amdgcn_s_setprio(0);
        __builtin_amdgcn_s_barrier();

        // ---- phase B mem: t=1 ds_reads + reduce of phase A accs ----
        s8b bf1[4];
#pragma unroll
        for (int ks = 0; ks < 4; ++ks)
            bf1[ks] = __builtin_bit_cast(s8b,
                *(const uint4*)(&buf[(32 + l31) * LROW + (2 * ks + half) * 8]));
        {
            float v = maxreduce32(pa0, pa1);
            v = fmaxf(v, __shfl_xor(v, 32));   // other half's 32 n-rows
            total += v;                        // bs col = l31 (replicated)
        }
        __builtin_amdgcn_s_barrier();
        asm volatile("s_waitcnt lgkmcnt(0)" ::: "memory");
        __builtin_amdgcn_sched_barrier(0);

        // ---- phase B MFMA cluster ----
        f32x16 pb0 = {0.f,0.f,0.f,0.f,0.f,0.f,0.f,0.f,
                      0.f,0.f,0.f,0.f,0.f,0.f,0.f,0.f};
        f32x16 pb1 = pb0;
        __builtin_amdgcn_s_setprio(1);
#pragma unroll
        for (int ks = 0; ks < 4; ++ks) {
            pb0 = MFMA32(af[0][ks], bf1[ks], pb0);
            pb1 = MFMA32(af[1][ks], bf1[ks], pb1);
        }
        __builtin_amdgcn_s_setprio(0);
        __builtin_amdgcn_s_barrier();

        // ---- tail: reduce phase B accs; publish slice s+1 ----
        {
            float v = maxreduce32(pb0, pb1);
            v = fmaxf(v, __shfl_xor(v, 32));
            total += v;                        // bs col = 32 + l31
        }
        if (s < 7) {
            *(uint4*)(&lx[(s + 1) & 1][sr * LROW + sc * 8]) = npf;
            __syncthreads();
        }
    }
    // Sum over the 32 bs columns (halves hold identical totals).
    total += __shfl_xor(total, 1);
    total += __shfl_xor(total, 2);
    total += __shfl_xor(total, 4);
    total += __shfl_xor(total, 8);
    total += __shfl_xor(total, 16);
    if (lane == 0) atomicAdd(out + batch * O_ + o, total);
}

// ---------------------------------------------------------------------------
extern "C" void kernel_launch(void* const* d_in, const int* in_sizes, int n_in,
                              void* d_out, int out_size, void* d_ws, size_t ws_size,
                              hipStream_t stream) {
    const float* Xs   = (const float*)d_in[0];   // [16,1024,300]
    const float* W    = (const float*)d_in[1];   // [64,300]
    const float* bias = (const float*)d_in[2];   // [64]
    const float* H    = (const float*)d_in[3];   // [256,64,64]
    float* out = (float*)d_out;                  // [16,256] f32

    char* ws = (char*)d_ws;
    __hip_bfloat16* Hb = (__hip_bfloat16*)(ws);            // 2,097,152 B
    __hip_bfloat16* Xc = (__hip_bfloat16*)(ws + 2097152);  // 2,097,152 B

    k_head <<<C_BLK + H_BLK + 1, 256, 0, stream>>>(Xs, W, bias, H, Xc, Hb, out);
    k_fused<<<B_ * (O_ / 8) * 2, 512, 0, stream>>>(Xc, Hb, out);
}